// Round 17
// baseline (86.467 us; speedup 1.0000x reference)
//
#include <hip/hip_runtime.h>
#include <math.h>

#define S_ 1024
#define T_ 32
#define SCALE_F 0.7071067811865476f

typedef unsigned int uint;
typedef unsigned short ushort;
typedef __bf16 bf16x8 __attribute__((ext_vector_type(8)));
typedef float f32x16 __attribute__((ext_vector_type(16)));

union FragU { uint4 q; bf16x8 v; };

#define MFMA(a, b, c) __builtin_amdgcn_mfma_f32_32x32x16_bf16((a), (b), (c), 0, 0, 0)

__device__ __forceinline__ uint rne16(float f) {
  uint u = __builtin_bit_cast(uint, f);
  u += 0x7fffu + ((u >> 16) & 1u);
  return u >> 16;
}

__device__ __forceinline__ float bf2f(ushort u) {
  return __builtin_bit_cast(float, ((uint)u) << 16);
}

__device__ __forceinline__ void split8a(const float* f, uint4& hi, uint4& lo) {
  uint h[8], m[8];
#pragma unroll
  for (int i = 0; i < 8; ++i) {
    uint u = __builtin_bit_cast(uint, f[i]);
    h[i] = u >> 16;
    float fh = __builtin_bit_cast(float, u & 0xffff0000u);
    m[i] = __builtin_bit_cast(uint, f[i] - fh) >> 16;
  }
  hi = make_uint4(h[0] | (h[1] << 16), h[2] | (h[3] << 16),
                  h[4] | (h[5] << 16), h[6] | (h[7] << 16));
  lo = make_uint4(m[0] | (m[1] << 16), m[2] | (m[3] << 16),
                  m[4] | (m[5] << 16), m[6] | (m[7] << 16));
}

__device__ __forceinline__ uint4 rne8(const float4& A, const float4& B) {
  float f[8] = {A.x, A.y, A.z, A.w, B.x, B.y, B.z, B.w};
  uint h[8];
#pragma unroll
  for (int i = 0; i < 8; ++i) h[i] = rne16(f[i]);
  return make_uint4(h[0] | (h[1] << 16), h[2] | (h[3] << 16),
                    h[4] | (h[5] << 16), h[6] | (h[7] << 16));
}

// ---------------------------------------------------------------------------
// Merged prep: blocks [0,3072) bulk f32->bf16 cvt; [3072,3200) cos/sin table;
// [3200,3328) A-matrix build. (Streaming, no inter-block reuse -> no swizzle.)
// ---------------------------------------------------------------------------
__global__ __launch_bounds__(256) void k_prep(
    const float* __restrict__ X, const float* __restrict__ Wq,
    const float* __restrict__ Wk, const float* __restrict__ Wv,
    const float* __restrict__ Wo, const float* __restrict__ tpl,
    const float* __restrict__ proj, ushort* __restrict__ Xb,
    ushort* __restrict__ Wqb, ushort* __restrict__ Wkb,
    ushort* __restrict__ Wvb, ushort* __restrict__ Wob,
    float* __restrict__ cs, ushort* __restrict__ Ahh,
    ushort* __restrict__ Ahl) {
  const int bid = blockIdx.x;
  const int tid = threadIdx.x;

  if (bid < 3072) {
    int i = bid * 256 + tid;
    const float* src;
    ushort* dst;
    int j;
    if (i < 262144)      { src = X;  dst = Xb;  j = i; }
    else if (i < 393216) { src = Wq; dst = Wqb; j = i - 262144; }
    else if (i < 524288) { src = Wk; dst = Wkb; j = i - 393216; }
    else if (i < 655360) { src = Wv; dst = Wvb; j = i - 524288; }
    else                 { src = Wo; dst = Wob; j = i - 655360; }
    float4 a = *reinterpret_cast<const float4*>(src + j * 8);
    float4 b = *reinterpret_cast<const float4*>(src + j * 8 + 4);
    *reinterpret_cast<uint4*>(dst + j * 8) = rne8(a, b);
    return;
  }

  if (bid < 3200) {
    int j = (bid - 3072) * 256 + tid;  // 0..32767
    int s = j >> 5, p = j & 31;
    float invf = powf(10000.0f, (-2.0f * p) / 64.0f);
    float sn, c;
    sincosf((float)s * invf, &sn, &c);
    cs[s * 64 + 2 * p] = c;
    cs[s * 64 + 2 * p + 1] = sn;
    return;
  }

  // A-matrix: ht = (bid-3200)*4 + wave
  {
    __shared__ float tn[4][64];
    int wid = tid >> 6, lane = tid & 63;
    int ht = (bid - 3200) * 4 + wid;
    int h = ht >> 5;
    float tv = tpl[ht * 64 + lane];
    float ss = tv * tv;
#pragma unroll
    for (int off2 = 1; off2 < 64; off2 <<= 1) ss += __shfl_xor(ss, off2);
    float rn = 1.0f / fmaxf(sqrtf(ss), 1e-12f);
    tn[wid][lane] = tv * rn;
    __syncthreads();
    float acc = 0.f;
#pragma unroll
    for (int j2 = 0; j2 < 64; ++j2)
      acc += proj[h * 64 + j2] * tn[wid][(lane - j2) & 63];
    float v = acc * 0.125f;
    uint u = __builtin_bit_cast(uint, v);
    uint hi = u >> 16;
    float fh = __builtin_bit_cast(float, u & 0xffff0000u);
    uint lo = __builtin_bit_cast(uint, v - fh) >> 16;
    Ahh[ht * 64 + lane] = (ushort)hi;
    Ahl[ht * 64 + lane] = (ushort)lo;
  }
}

// ---------------------------------------------------------------------------
// QKV GEMM (validated round-14 body) + XCD-aware block swizzle:
// flat id -> XCD k = flat&7 owns a 4x8 (x,y) chunk across all z, so each
// XCD's L2 holds 4 W-panels x3 (1.5MB) + 8 X-panels (2MB) instead of
// re-fetching X on all 8 XCDs (the measured 36MB over-fetch).
// ---------------------------------------------------------------------------
__global__ __launch_bounds__(256) void k_qkv(
    const ushort* __restrict__ Xb,
    const ushort* __restrict__ Wqb, const ushort* __restrict__ Wkb,
    const ushort* __restrict__ Wvb,
    const ushort* __restrict__ Ahh, const ushort* __restrict__ Ahl,
    const float* __restrict__ cs,
    ushort* __restrict__ Qs, ushort* __restrict__ Ks,
    ushort* __restrict__ Vt) {
  __shared__ __align__(16) char smem[34816];

  // ---- XCD swizzle: bijective remap of 768 blocks ----
  const int flat = blockIdx.x + (blockIdx.y << 4) + (blockIdx.z << 8);
  const int xcd = flat & 7;
  const int c = flat >> 3;        // 0..95
  const int z = c >> 5;           // 0..2
  const int bx = ((xcd & 3) << 2) + (c & 3);        // 0..15
  const int by = ((xcd >> 2) << 3) + ((c >> 2) & 7);// 0..15

  const ushort* Wm = (z == 0) ? Wqb : (z == 1) ? Wkb : Wvb;
  const int m0 = by * 128;
  const int n0 = bx * 64;
  const int h = bx;

  const int tid = threadIdx.x;
  const int l = tid & 63;
  const int wid = tid >> 6;
  const int wr = wid >> 1, wc = wid & 1;
  const int l31 = l & 31, lhi = l >> 5;

  const int sr = tid >> 2;
  const int sc = tid & 3;

  const int offA0 = (sr) * 64 + ((sc ^ ((sr >> 1) & 3)) << 4);
  const int offA1 = (sr + 64) * 64 + ((sc ^ (((sr + 64) >> 1) & 3)) << 4);
  const int offB = 8192 + sr * 64 + ((sc ^ ((sr >> 1) & 3)) << 4);

  const ushort* apsrc0 = Xb + (size_t)(m0 + sr) * 1024 + sc * 8;
  const ushort* apsrc1 = Xb + (size_t)(m0 + sr + 64) * 1024 + sc * 8;
  const ushort* bpsrc = Wm + (size_t)(n0 + sr) * 1024 + sc * 8;

  f32x16 acc0 = 0.0f, acc1 = 0.0f;

  {
    *reinterpret_cast<uint4*>(smem + offA0) =
        *reinterpret_cast<const uint4*>(apsrc0);
    *reinterpret_cast<uint4*>(smem + offA1) =
        *reinterpret_cast<const uint4*>(apsrc1);
    *reinterpret_cast<uint4*>(smem + offB) =
        *reinterpret_cast<const uint4*>(bpsrc);
  }
  uint4 ra0 = *reinterpret_cast<const uint4*>(apsrc0 + 32);
  uint4 ra1 = *reinterpret_cast<const uint4*>(apsrc1 + 32);
  uint4 rb = *reinterpret_cast<const uint4*>(bpsrc + 32);
  __syncthreads();

  int cur = 0;
#pragma unroll 4
  for (int t = 0; t < 32; ++t) {
    uint4 na0, na1, nb;
    if (t < 30) {
      const int kn = (t + 2) * 32;
      na0 = *reinterpret_cast<const uint4*>(apsrc0 + kn);
      na1 = *reinterpret_cast<const uint4*>(apsrc1 + kn);
      nb = *reinterpret_cast<const uint4*>(bpsrc + kn);
    }

    const char* base = smem + cur * 12288;
#pragma unroll
    for (int kst = 0; kst < 2; ++kst) {
      FragU ah0, ah1, bh;
      {
        int row = wr * 64 + l31;
        int cc = (kst * 2 + lhi) ^ ((row >> 1) & 3);
        ah0.q = *reinterpret_cast<const uint4*>(base + row * 64 + cc * 16);
      }
      {
        int row = wr * 64 + 32 + l31;
        int cc = (kst * 2 + lhi) ^ ((row >> 1) & 3);
        ah1.q = *reinterpret_cast<const uint4*>(base + row * 64 + cc * 16);
      }
      {
        int brow = wc * 32 + l31;
        int bcc = (kst * 2 + lhi) ^ ((brow >> 1) & 3);
        bh.q = *reinterpret_cast<const uint4*>(base + 8192 + brow * 64 + bcc * 16);
      }
      acc0 = MFMA(ah0.v, bh.v, acc0);
      acc1 = MFMA(ah1.v, bh.v, acc1);
    }

    if (t < 31) {
      char* dst = smem + (cur ^ 1) * 12288;
      *reinterpret_cast<uint4*>(dst + offA0) = ra0;
      *reinterpret_cast<uint4*>(dst + offA1) = ra1;
      *reinterpret_cast<uint4*>(dst + offB) = rb;
      __syncthreads();
      cur ^= 1;
      if (t < 30) { ra0 = na0; ra1 = na1; rb = nb; }
    }
  }

  if (z == 2) {
    int d = wc * 32 + l31;
#pragma unroll
    for (int fm = 0; fm < 2; ++fm) {
      const f32x16& a = fm ? acc1 : acc0;
#pragma unroll
      for (int j = 0; j < 16; ++j) {
        int rl = fm * 32 + (j & 3) + ((j >> 2) & 3) * 8 + 4 * lhi;
        int m = m0 + wr * 64 + rl;
        int b = m >> 10, s = m & 1023;
        Vt[((size_t)((b * 16 + h) * 64 + d)) * 1024 + s] = (ushort)rne16(a[j]);
      }
    }
    return;
  }

  ushort* Sig = (z == 0) ? Qs : Ks;
  float* dmp = reinterpret_cast<float*>(smem);  // [128][68] f32
  __syncthreads();
#pragma unroll
  for (int fm = 0; fm < 2; ++fm) {
    const f32x16& a = fm ? acc1 : acc0;
#pragma unroll
    for (int j = 0; j < 16; ++j) {
      int rl = fm * 32 + (j & 3) + ((j >> 2) & 3) * 8 + 4 * lhi;
      dmp[(wr * 64 + rl) * 68 + wc * 32 + l31] = a[j];
    }
  }
  __syncthreads();

  int srow = wr * 64 + wc * 32 + l31;
  int sq = (m0 + srow) & 1023;
  f32x16 sacc = 0.0f;
#pragma unroll
  for (int kst = 0; kst < 4; ++kst) {
    const float* dp = &dmp[srow * 68 + kst * 16 + lhi * 8];
    float4 x0 = *reinterpret_cast<const float4*>(dp);
    float4 x1 = *reinterpret_cast<const float4*>(dp + 4);
    const float* cp = &cs[sq * 64 + kst * 16 + lhi * 8];
    float4 c0 = *reinterpret_cast<const float4*>(cp);
    float4 c1 = *reinterpret_cast<const float4*>(cp + 4);
    float r[8];
    r[0] = x0.x * c0.x - x0.y * c0.y;
    r[1] = x0.x * c0.y + x0.y * c0.x;
    r[2] = x0.z * c0.z - x0.w * c0.w;
    r[3] = x0.z * c0.w + x0.w * c0.z;
    r[4] = x1.x * c1.x - x1.y * c1.y;
    r[5] = x1.x * c1.y + x1.y * c1.x;
    r[6] = x1.z * c1.z - x1.w * c1.w;
    r[7] = x1.z * c1.w + x1.w * c1.z;
    FragU ah, al;
    split8a(r, ah.q, al.q);
    size_t boff = ((size_t)(h * 32 + l31) * 64 + kst * 16 + lhi * 8);
    FragU bh, bl;
    bh.q = *reinterpret_cast<const uint4*>(Ahh + boff);
    bl.q = *reinterpret_cast<const uint4*>(Ahl + boff);
    sacc = MFMA(al.v, bh.v, sacc);
    sacc = MFMA(ah.v, bl.v, sacc);
    sacc = MFMA(ah.v, bh.v, sacc);
  }
#pragma unroll
  for (int j = 0; j < 16; ++j) {
    float v = sacc[j];
    float ss = v * v;
    ss += __shfl_xor(ss, 1);
    ss += __shfl_xor(ss, 2);
    ss += __shfl_xor(ss, 4);
    ss += __shfl_xor(ss, 8);
    ss += __shfl_xor(ss, 16);
    float rn = 1.0f / fmaxf(sqrtf(ss), 1e-12f);
    int rl = (j & 3) + ((j >> 2) & 3) * 8 + 4 * lhi;
    int m = m0 + wr * 64 + wc * 32 + rl;
    int bb = m >> 10, s2 = m & 1023;
    Sig[(((size_t)(bb * 16 + h)) * 1024 + s2) * 32 + l31] =
        (ushort)rne16(v * rn);
  }
}

// ---------------------------------------------------------------------------
// Fused split-K MFMA attention (validated round-14 body) + XCD swizzle:
// XCD k owns 4 consecutive bh (K/V slab 768KB L2-resident) x all q-tiles.
// ---------------------------------------------------------------------------
__global__ __launch_bounds__(512) void k_attn(const ushort* __restrict__ Qs,
                                              const ushort* __restrict__ Ks,
                                              const ushort* __restrict__ Vt,
                                              ushort* __restrict__ O) {
  __shared__ __align__(16) char smem[34816];
  ushort* pm = reinterpret_cast<ushort*>(smem);
  float* pd = reinterpret_cast<float*>(smem + 24576);

  // ---- XCD swizzle: bijective remap of 512 blocks ----
  const int flat = blockIdx.x + (blockIdx.y << 4);
  const int xcd = flat & 7;
  const int c = flat >> 3;            // 0..63
  const int bh = (xcd << 2) + (c & 3);// 0..31
  const int qx = c >> 2;              // 0..15

  const int tid = threadIdx.x;
  const int l = tid & 63;
  const int wid = tid >> 6;       // 0..7
  const int zc = wid >> 1;        // K chunk 0..3
  const int qh = wid & 1;         // q half 0..1
  const int l31 = l & 31, lhi = l >> 5;
  const int q0 = qx * 64 + qh * 32;

  ushort* myp = reinterpret_cast<ushort*>(smem) + wid * (32 * 68);

  FragU aq0, aq1;
  {
    const ushort* qp = Qs + ((size_t)bh * 1024 + q0 + l31) * 32 + lhi * 8;
    aq0.q = *reinterpret_cast<const uint4*>(qp);
    aq1.q = *reinterpret_cast<const uint4*>(qp + 16);
  }

  const ushort* kbase = Ks + (size_t)bh * 1024 * 32;
  const ushort* vbase = Vt + (size_t)bh * 64 * 1024;

  f32x16 oacc0 = 0.0f, oacc1 = 0.0f;
  float pden[16];
#pragma unroll
  for (int r = 0; r < 16; ++r) pden[r] = 0.f;

  const int ktBeg = zc * 4;
  FragU kc00, kc01, kc10, kc11;
  {
    const ushort* kp0 = kbase + (size_t)(ktBeg * 64 + l31) * 32 + lhi * 8;
    const ushort* kp1 = kbase + (size_t)(ktBeg * 64 + 32 + l31) * 32 + lhi * 8;
    kc00.q = *reinterpret_cast<const uint4*>(kp0);
    kc01.q = *reinterpret_cast<const uint4*>(kp0 + 16);
    kc10.q = *reinterpret_cast<const uint4*>(kp1);
    kc11.q = *reinterpret_cast<const uint4*>(kp1 + 16);
  }

#pragma unroll
  for (int ki = 0; ki < 4; ++ki) {
    const int kt = ktBeg + ki;
    const int k0 = kt * 64;

    FragU vv00, vv01, vv10, vv11, vv20, vv21, vv30, vv31;
    {
      const ushort* vp = vbase + (size_t)l31 * 1024 + k0 + lhi * 8;
      vv00.q = *reinterpret_cast<const uint4*>(vp);
      vv01.q = *reinterpret_cast<const uint4*>(vp + 32 * 1024);
      vv10.q = *reinterpret_cast<const uint4*>(vp + 16);
      vv11.q = *reinterpret_cast<const uint4*>(vp + 16 + 32 * 1024);
      vv20.q = *reinterpret_cast<const uint4*>(vp + 32);
      vv21.q = *reinterpret_cast<const uint4*>(vp + 32 + 32 * 1024);
      vv30.q = *reinterpret_cast<const uint4*>(vp + 48);
      vv31.q = *reinterpret_cast<const uint4*>(vp + 48 + 32 * 1024);
    }

    f32x16 sacc0 = 0.0f, sacc1 = 0.0f;
    sacc0 = MFMA(aq0.v, kc00.v, sacc0);
    sacc0 = MFMA(aq1.v, kc01.v, sacc0);
    sacc1 = MFMA(aq0.v, kc10.v, sacc1);
    sacc1 = MFMA(aq1.v, kc11.v, sacc1);

    FragU kn00, kn01, kn10, kn11;
    if (ki < 3) {
      const ushort* kp0 = kbase + (size_t)((kt + 1) * 64 + l31) * 32 + lhi * 8;
      const ushort* kp1 =
          kbase + (size_t)((kt + 1) * 64 + 32 + l31) * 32 + lhi * 8;
      kn00.q = *reinterpret_cast<const uint4*>(kp0);
      kn01.q = *reinterpret_cast<const uint4*>(kp0 + 16);
      kn10.q = *reinterpret_cast<const uint4*>(kp1);
      kn11.q = *reinterpret_cast<const uint4*>(kp1 + 16);
    }

#pragma unroll
    for (int r = 0; r < 16; ++r) {
      float e0 = __expf(sacc0[r] * SCALE_F);
      float e1 = __expf(sacc1[r] * SCALE_F);
      pden[r] += e0 + e1;
      int q = (r & 3) + ((r >> 2) << 3) + 4 * lhi;
      myp[q * 68 + l31] = (ushort)rne16(e0);
      myp[q * 68 + 32 + l31] = (ushort)rne16(e1);
    }
    __builtin_amdgcn_wave_barrier();

#pragma unroll
    for (int kst = 0; kst < 4; ++kst) {
      FragU ap;
      const ushort* pp = myp + l31 * 68 + kst * 16 + lhi * 8;
      uint2 plo = *reinterpret_cast<const uint2*>(pp);
      uint2 phi = *reinterpret_cast<const uint2*>(pp + 4);
      ap.q = make_uint4(plo.x, plo.y, phi.x, phi.y);
      const FragU& b0 = (kst == 0) ? vv00 : (kst == 1) ? vv10 : (kst == 2) ? vv20 : vv30;
      const FragU& b1 = (kst == 0) ? vv01 : (kst == 1) ? vv11 : (kst == 2) ? vv21 : vv31;
      oacc0 = MFMA(ap.v, b0.v, oacc0);
      oacc1 = MFMA(ap.v, b1.v, oacc1);
    }

    if (ki < 3) { kc00 = kn00; kc01 = kn01; kc10 = kn10; kc11 = kn11; }
  }

#pragma unroll
  for (int r = 0; r < 16; ++r) {
    float s = pden[r];
    s += __shfl_xor(s, 1);
    s += __shfl_xor(s, 2);
    s += __shfl_xor(s, 4);
    s += __shfl_xor(s, 8);
    s += __shfl_xor(s, 16);
    pden[r] = s;
  }

  __syncthreads();  // all waves done with their P tiles; safe to alias
  if (zc > 0) {
    const int mi = (zc - 1) * 2 + qh;
#pragma unroll
    for (int r = 0; r < 16; ++r) {
      int q = (r & 3) + ((r >> 2) << 3) + 4 * lhi;
      pm[(mi * 32 + q) * 64 + l31] = (ushort)rne16(oacc0[r]);
      pm[(mi * 32 + q) * 64 + 32 + l31] = (ushort)rne16(oacc1[r]);
      if (l31 == 0) pd[mi * 32 + q] = pden[r];
    }
  }
  __syncthreads();
  if (zc == 0) {
    const int b = bh >> 4, h = bh & 15;
#pragma unroll
    for (int r = 0; r < 16; ++r) {
      int q = (r & 3) + ((r >> 2) << 3) + 4 * lhi;
      float v0 = oacc0[r], v1 = oacc1[r], den = pden[r];
#pragma unroll
      for (int zz = 0; zz < 3; ++zz) {
        int mi = zz * 2 + qh;
        v0 += bf2f(pm[(mi * 32 + q) * 64 + l31]);
        v1 += bf2f(pm[(mi * 32 + q) * 64 + 32 + l31]);
        den += pd[mi * 32 + q];
      }
      float rden = 1.0f / den;
      size_t row = ((size_t)(b * 1024 + q0 + q)) * 1024 + h * 64;
      O[row + l31] = (ushort)rne16(v0 * rden);
      O[row + 32 + l31] = (ushort)rne16(v1 * rden);
    }
  }
}

// ---------------------------------------------------------------------------
// Final projection (validated round-10 body) + XCD swizzle (4x16 chunks).
// ---------------------------------------------------------------------------
__global__ __launch_bounds__(256) void k_final(const ushort* __restrict__ Xb,
                                               const ushort* __restrict__ Wb,
                                               float* __restrict__ Y) {
  __shared__ __align__(16) char smem[16384];

  // ---- XCD swizzle: bijective remap of 512 blocks ----
  const int flat = blockIdx.x + (blockIdx.y << 4);
  const int xcd = flat & 7;
  const int c = flat >> 3;                    // 0..63
  const int bx = ((xcd & 3) << 2) + (c & 3);  // 0..15
  const int by = ((xcd >> 2) << 4) + (c >> 2);// 0..31

  const int m0 = by * 64;
  const int n0 = bx * 64;
  const int tid = threadIdx.x;
  const int l = tid & 63;
  const int wid = tid >> 6;
  const int wr = wid >> 1, wc = wid & 1;
  const int l31 = l & 31, lhi = l >> 5;
  const int sr = tid >> 2;
  const int sc = tid & 3;

  const int offA = sr * 64 + ((sc ^ ((sr >> 1) & 3)) << 4);
  const int offB = 4096 + offA;
  const ushort* apsrc = Xb + (size_t)(m0 + sr) * 1024 + sc * 8;
  const ushort* bpsrc = Wb + (size_t)(n0 + sr) * 1024 + sc * 8;

  f32x16 acc = 0.0f;

  {
    *reinterpret_cast<uint4*>(smem + offA) =
        *reinterpret_cast<const uint4*>(apsrc);
    *reinterpret_cast<uint4*>(smem + offB) =
        *reinterpret_cast<const uint4*>(bpsrc);
  }
  uint4 ra = *reinterpret_cast<const uint4*>(apsrc + 32);
  uint4 rb = *reinterpret_cast<const uint4*>(bpsrc + 32);
  __syncthreads();

  int cur = 0;
#pragma unroll 4
  for (int t = 0; t < 32; ++t) {
    uint4 na, nb;
    if (t < 30) {
      const int kn = (t + 2) * 32;
      na = *reinterpret_cast<const uint4*>(apsrc + kn);
      nb = *reinterpret_cast<const uint4*>(bpsrc + kn);
    }

    const char* base = smem + cur * 8192;
#pragma unroll
    for (int kst = 0; kst < 2; ++kst) {
      FragU ah, bh;
      int row = wr * 32 + l31;
      int cc = (kst * 2 + lhi) ^ ((row >> 1) & 3);
      ah.q = *reinterpret_cast<const uint4*>(base + row * 64 + cc * 16);
      int brow = wc * 32 + l31;
      int bcc = (kst * 2 + lhi) ^ ((brow >> 1) & 3);
      bh.q = *reinterpret_cast<const uint4*>(base + 4096 + brow * 64 + bcc * 16);
      acc = MFMA(ah.v, bh.v, acc);
    }

    if (t < 31) {
      char* dst = smem + (cur ^ 1) * 8192;
      *reinterpret_cast<uint4*>(dst + offA) = ra;
      *reinterpret_cast<uint4*>(dst + offB) = rb;
      __syncthreads();
      cur ^= 1;
      if (t < 30) { ra = na; rb = nb; }
    }
  }

#pragma unroll
  for (int j = 0; j < 16; ++j) {
    int rl = (j & 3) + ((j >> 2) & 3) * 8 + 4 * lhi;
    int m = m0 + wr * 32 + rl;
    Y[(size_t)m * 1024 + n0 + wc * 32 + l31] = acc[j];
  }
}

// ---------------------------------------------------------------------------
extern "C" void kernel_launch(void* const* d_in, const int* in_sizes, int n_in,
                              void* d_out, int out_size, void* d_ws,
                              size_t ws_size, hipStream_t stream) {
  const float* x = (const float*)d_in[0];
  const float* Wq = (const float*)d_in[1];
  const float* Wk = (const float*)d_in[2];
  const float* Wv = (const float*)d_in[3];
  const float* Wo = (const float*)d_in[4];
  const float* tpl = (const float*)d_in[5];
  const float* proj = (const float*)d_in[6];
  float* out = (float*)d_out;

  char* ws = (char*)d_ws;
  size_t off = 0;
  auto alloc = [&](size_t bytes) {
    void* p = ws + off;
    off += (bytes + 255) & ~(size_t)255;
    return p;
  };

  const size_t MB = 1024 * 1024;
  bool big = ws_size >= 22 * MB;

  ushort *Xb, *Wvb, *obuf;
  float* cs;
  ushort *Ahh, *Ahl, *Wqb, *Wkb, *Wob, *qs, *ks, *vt;

  if (big) {
    Xb = (ushort*)alloc(4 * MB);
    cs = (float*)alloc((size_t)1024 * 64 * 4);
    Ahh = (ushort*)alloc((size_t)16 * 32 * 64 * 2);
    Ahl = (ushort*)alloc((size_t)16 * 32 * 64 * 2);
    Wqb = (ushort*)alloc(2 * MB);
    Wkb = (ushort*)alloc(2 * MB);
    Wvb = (ushort*)alloc(2 * MB);
    Wob = (ushort*)alloc(2 * MB);
    qs = (ushort*)alloc(2 * MB);
    ks = (ushort*)alloc(2 * MB);
    vt = (ushort*)alloc(4 * MB);
    obuf = Xb;  // Xb dead after k_qkv
  } else {
    cs = (float*)alloc((size_t)1024 * 64 * 4);
    Ahh = (ushort*)alloc((size_t)16 * 32 * 64 * 2);
    Ahl = (ushort*)alloc((size_t)16 * 32 * 64 * 2);
    Wqb = (ushort*)alloc(2 * MB);
    Wkb = (ushort*)alloc(2 * MB);
    Wob = (ushort*)alloc(2 * MB);
    qs = (ushort*)alloc(2 * MB);
    ks = (ushort*)alloc(2 * MB);
    vt = (ushort*)alloc(4 * MB);
    obuf = (ushort*)ws;  // aliases [cs..Wkb] (dead after k_qkv)
    Xb = (ushort*)d_out;
    Wvb = (ushort*)((char*)d_out + 4 * MB);
  }

  k_prep<<<dim3(3328), dim3(256), 0, stream>>>(x, Wq, Wk, Wv, Wo, tpl, proj,
                                               Xb, Wqb, Wkb, Wvb, Wob, cs, Ahh,
                                               Ahl);
  k_qkv<<<dim3(16, 16, 3), dim3(256), 0, stream>>>(Xb, Wqb, Wkb, Wvb, Ahh, Ahl,
                                                   cs, qs, ks, vt);
  k_attn<<<dim3(16, 32), dim3(512), 0, stream>>>(qs, ks, vt, obuf);
  k_final<<<dim3(16, 32), dim3(256), 0, stream>>>(obuf, Wob, out);
}

// Round 18
// 83.732 us; speedup vs baseline: 1.0327x; 1.0327x over previous
//
#include <hip/hip_runtime.h>
#include <math.h>

#define S_ 1024
#define T_ 32
#define SCALE_F 0.7071067811865476f

typedef unsigned int uint;
typedef unsigned short ushort;
typedef __bf16 bf16x8 __attribute__((ext_vector_type(8)));
typedef float f32x16 __attribute__((ext_vector_type(16)));

union FragU { uint4 q; bf16x8 v; };

#define MFMA(a, b, c) __builtin_amdgcn_mfma_f32_32x32x16_bf16((a), (b), (c), 0, 0, 0)

__device__ __forceinline__ uint rne16(float f) {
  uint u = __builtin_bit_cast(uint, f);
  u += 0x7fffu + ((u >> 16) & 1u);
  return u >> 16;
}

__device__ __forceinline__ float bf2f(ushort u) {
  return __builtin_bit_cast(float, ((uint)u) << 16);
}

__device__ __forceinline__ void split8a(const float* f, uint4& hi, uint4& lo) {
  uint h[8], m[8];
#pragma unroll
  for (int i = 0; i < 8; ++i) {
    uint u = __builtin_bit_cast(uint, f[i]);
    h[i] = u >> 16;
    float fh = __builtin_bit_cast(float, u & 0xffff0000u);
    m[i] = __builtin_bit_cast(uint, f[i] - fh) >> 16;
  }
  hi = make_uint4(h[0] | (h[1] << 16), h[2] | (h[3] << 16),
                  h[4] | (h[5] << 16), h[6] | (h[7] << 16));
  lo = make_uint4(m[0] | (m[1] << 16), m[2] | (m[3] << 16),
                  m[4] | (m[5] << 16), m[6] | (m[7] << 16));
}

__device__ __forceinline__ uint4 rne8(const float4& A, const float4& B) {
  float f[8] = {A.x, A.y, A.z, A.w, B.x, B.y, B.z, B.w};
  uint h[8];
#pragma unroll
  for (int i = 0; i < 8; ++i) h[i] = rne16(f[i]);
  return make_uint4(h[0] | (h[1] << 16), h[2] | (h[3] << 16),
                    h[4] | (h[5] << 16), h[6] | (h[7] << 16));
}

// ---------------------------------------------------------------------------
// Merged prep: blocks [0,3072) bulk f32->bf16 cvt; [3072,3200) cos/sin table;
// [3200,3328) A-matrix build (4 ht per block, one per wave).
// ---------------------------------------------------------------------------
__global__ __launch_bounds__(256) void k_prep(
    const float* __restrict__ X, const float* __restrict__ Wq,
    const float* __restrict__ Wk, const float* __restrict__ Wv,
    const float* __restrict__ Wo, const float* __restrict__ tpl,
    const float* __restrict__ proj, ushort* __restrict__ Xb,
    ushort* __restrict__ Wqb, ushort* __restrict__ Wkb,
    ushort* __restrict__ Wvb, ushort* __restrict__ Wob,
    float* __restrict__ cs, ushort* __restrict__ Ahh,
    ushort* __restrict__ Ahl) {
  const int bid = blockIdx.x;
  const int tid = threadIdx.x;

  if (bid < 3072) {
    int i = bid * 256 + tid;
    const float* src;
    ushort* dst;
    int j;
    if (i < 262144)      { src = X;  dst = Xb;  j = i; }
    else if (i < 393216) { src = Wq; dst = Wqb; j = i - 262144; }
    else if (i < 524288) { src = Wk; dst = Wkb; j = i - 393216; }
    else if (i < 655360) { src = Wv; dst = Wvb; j = i - 524288; }
    else                 { src = Wo; dst = Wob; j = i - 655360; }
    float4 a = *reinterpret_cast<const float4*>(src + j * 8);
    float4 b = *reinterpret_cast<const float4*>(src + j * 8 + 4);
    *reinterpret_cast<uint4*>(dst + j * 8) = rne8(a, b);
    return;
  }

  if (bid < 3200) {
    int j = (bid - 3072) * 256 + tid;  // 0..32767
    int s = j >> 5, p = j & 31;
    float invf = powf(10000.0f, (-2.0f * p) / 64.0f);
    float sn, c;
    sincosf((float)s * invf, &sn, &c);
    cs[s * 64 + 2 * p] = c;
    cs[s * 64 + 2 * p + 1] = sn;
    return;
  }

  // A-matrix: ht = (bid-3200)*4 + wave
  {
    __shared__ float tn[4][64];
    int wid = tid >> 6, lane = tid & 63;
    int ht = (bid - 3200) * 4 + wid;
    int h = ht >> 5;
    float tv = tpl[ht * 64 + lane];
    float ss = tv * tv;
#pragma unroll
    for (int off2 = 1; off2 < 64; off2 <<= 1) ss += __shfl_xor(ss, off2);
    float rn = 1.0f / fmaxf(sqrtf(ss), 1e-12f);
    tn[wid][lane] = tv * rn;
    __syncthreads();
    float acc = 0.f;
#pragma unroll
    for (int j2 = 0; j2 < 64; ++j2)
      acc += proj[h * 64 + j2] * tn[wid][(lane - j2) & 63];
    float v = acc * 0.125f;
    uint u = __builtin_bit_cast(uint, v);
    uint hi = u >> 16;
    float fh = __builtin_bit_cast(float, u & 0xffff0000u);
    uint lo = __builtin_bit_cast(uint, v - fh) >> 16;
    Ahh[ht * 64 + lane] = (ushort)hi;
    Ahl[ht * 64 + lane] = (ushort)lo;
  }
}

// ---------------------------------------------------------------------------
// QKV GEMM (validated round-11/13/14/16): z in {0,1,2}, depth-2 pipeline,
// 2 LDS buffers + reg-staged tile. ~100 VGPR, 3 blocks/CU.
// ---------------------------------------------------------------------------
__global__ __launch_bounds__(256) void k_qkv(
    const ushort* __restrict__ Xb,
    const ushort* __restrict__ Wqb, const ushort* __restrict__ Wkb,
    const ushort* __restrict__ Wvb,
    const ushort* __restrict__ Ahh, const ushort* __restrict__ Ahl,
    const float* __restrict__ cs,
    ushort* __restrict__ Qs, ushort* __restrict__ Ks,
    ushort* __restrict__ Vt) {
  __shared__ __align__(16) char smem[34816];

  const int z = blockIdx.z;
  const ushort* Wm = (z == 0) ? Wqb : (z == 1) ? Wkb : Wvb;
  const int m0 = blockIdx.y * 128;
  const int n0 = blockIdx.x * 64;
  const int h = blockIdx.x;

  const int tid = threadIdx.x;
  const int l = tid & 63;
  const int wid = tid >> 6;
  const int wr = wid >> 1, wc = wid & 1;
  const int l31 = l & 31, lhi = l >> 5;

  const int sr = tid >> 2;
  const int sc = tid & 3;

  const int offA0 = (sr) * 64 + ((sc ^ ((sr >> 1) & 3)) << 4);
  const int offA1 = (sr + 64) * 64 + ((sc ^ (((sr + 64) >> 1) & 3)) << 4);
  const int offB = 8192 + sr * 64 + ((sc ^ ((sr >> 1) & 3)) << 4);

  const ushort* apsrc0 = Xb + (size_t)(m0 + sr) * 1024 + sc * 8;
  const ushort* apsrc1 = Xb + (size_t)(m0 + sr + 64) * 1024 + sc * 8;
  const ushort* bpsrc = Wm + (size_t)(n0 + sr) * 1024 + sc * 8;

  f32x16 acc0 = 0.0f, acc1 = 0.0f;

  {
    *reinterpret_cast<uint4*>(smem + offA0) =
        *reinterpret_cast<const uint4*>(apsrc0);
    *reinterpret_cast<uint4*>(smem + offA1) =
        *reinterpret_cast<const uint4*>(apsrc1);
    *reinterpret_cast<uint4*>(smem + offB) =
        *reinterpret_cast<const uint4*>(bpsrc);
  }
  uint4 ra0 = *reinterpret_cast<const uint4*>(apsrc0 + 32);
  uint4 ra1 = *reinterpret_cast<const uint4*>(apsrc1 + 32);
  uint4 rb = *reinterpret_cast<const uint4*>(bpsrc + 32);
  __syncthreads();

  int cur = 0;
#pragma unroll 4
  for (int t = 0; t < 32; ++t) {
    uint4 na0, na1, nb;
    if (t < 30) {
      const int kn = (t + 2) * 32;
      na0 = *reinterpret_cast<const uint4*>(apsrc0 + kn);
      na1 = *reinterpret_cast<const uint4*>(apsrc1 + kn);
      nb = *reinterpret_cast<const uint4*>(bpsrc + kn);
    }

    const char* base = smem + cur * 12288;
#pragma unroll
    for (int kst = 0; kst < 2; ++kst) {
      FragU ah0, ah1, bh;
      {
        int row = wr * 64 + l31;
        int cc = (kst * 2 + lhi) ^ ((row >> 1) & 3);
        ah0.q = *reinterpret_cast<const uint4*>(base + row * 64 + cc * 16);
      }
      {
        int row = wr * 64 + 32 + l31;
        int cc = (kst * 2 + lhi) ^ ((row >> 1) & 3);
        ah1.q = *reinterpret_cast<const uint4*>(base + row * 64 + cc * 16);
      }
      {
        int brow = wc * 32 + l31;
        int bcc = (kst * 2 + lhi) ^ ((brow >> 1) & 3);
        bh.q = *reinterpret_cast<const uint4*>(base + 8192 + brow * 64 + bcc * 16);
      }
      acc0 = MFMA(ah0.v, bh.v, acc0);
      acc1 = MFMA(ah1.v, bh.v, acc1);
    }

    if (t < 31) {
      char* dst = smem + (cur ^ 1) * 12288;
      *reinterpret_cast<uint4*>(dst + offA0) = ra0;
      *reinterpret_cast<uint4*>(dst + offA1) = ra1;
      *reinterpret_cast<uint4*>(dst + offB) = rb;
      __syncthreads();
      cur ^= 1;
      if (t < 30) { ra0 = na0; ra1 = na1; rb = nb; }
    }
  }

  if (z == 2) {
    int d = wc * 32 + l31;
#pragma unroll
    for (int fm = 0; fm < 2; ++fm) {
      const f32x16& a = fm ? acc1 : acc0;
#pragma unroll
      for (int j = 0; j < 16; ++j) {
        int rl = fm * 32 + (j & 3) + ((j >> 2) & 3) * 8 + 4 * lhi;
        int m = m0 + wr * 64 + rl;
        int b = m >> 10, s = m & 1023;
        Vt[((size_t)((b * 16 + h) * 64 + d)) * 1024 + s] = (ushort)rne16(a[j]);
      }
    }
    return;
  }

  ushort* Sig = (z == 0) ? Qs : Ks;
  float* dmp = reinterpret_cast<float*>(smem);  // [128][68] f32
  __syncthreads();
#pragma unroll
  for (int fm = 0; fm < 2; ++fm) {
    const f32x16& a = fm ? acc1 : acc0;
#pragma unroll
    for (int j = 0; j < 16; ++j) {
      int rl = fm * 32 + (j & 3) + ((j >> 2) & 3) * 8 + 4 * lhi;
      dmp[(wr * 64 + rl) * 68 + wc * 32 + l31] = a[j];
    }
  }
  __syncthreads();

  int srow = wr * 64 + wc * 32 + l31;
  int sq = (m0 + srow) & 1023;
  f32x16 sacc = 0.0f;
#pragma unroll
  for (int kst = 0; kst < 4; ++kst) {
    const float* dp = &dmp[srow * 68 + kst * 16 + lhi * 8];
    float4 x0 = *reinterpret_cast<const float4*>(dp);
    float4 x1 = *reinterpret_cast<const float4*>(dp + 4);
    const float* cp = &cs[sq * 64 + kst * 16 + lhi * 8];
    float4 c0 = *reinterpret_cast<const float4*>(cp);
    float4 c1 = *reinterpret_cast<const float4*>(cp + 4);
    float r[8];
    r[0] = x0.x * c0.x - x0.y * c0.y;
    r[1] = x0.x * c0.y + x0.y * c0.x;
    r[2] = x0.z * c0.z - x0.w * c0.w;
    r[3] = x0.z * c0.w + x0.w * c0.z;
    r[4] = x1.x * c1.x - x1.y * c1.y;
    r[5] = x1.x * c1.y + x1.y * c1.x;
    r[6] = x1.z * c1.z - x1.w * c1.w;
    r[7] = x1.z * c1.w + x1.w * c1.z;
    FragU ah, al;
    split8a(r, ah.q, al.q);
    size_t boff = ((size_t)(h * 32 + l31) * 64 + kst * 16 + lhi * 8);
    FragU bh, bl;
    bh.q = *reinterpret_cast<const uint4*>(Ahh + boff);
    bl.q = *reinterpret_cast<const uint4*>(Ahl + boff);
    sacc = MFMA(al.v, bh.v, sacc);
    sacc = MFMA(ah.v, bl.v, sacc);
    sacc = MFMA(ah.v, bh.v, sacc);
  }
#pragma unroll
  for (int j = 0; j < 16; ++j) {
    float v = sacc[j];
    float ss = v * v;
    ss += __shfl_xor(ss, 1);
    ss += __shfl_xor(ss, 2);
    ss += __shfl_xor(ss, 4);
    ss += __shfl_xor(ss, 8);
    ss += __shfl_xor(ss, 16);
    float rn = 1.0f / fmaxf(sqrtf(ss), 1e-12f);
    int rl = (j & 3) + ((j >> 2) & 3) * 8 + 4 * lhi;
    int m = m0 + wr * 64 + wc * 32 + rl;
    int bb = m >> 10, s2 = m & 1023;
    Sig[(((size_t)(bb * 16 + h)) * 1024 + s2) * 32 + l31] =
        (ushort)rne16(v * rn);
  }
}

// ---------------------------------------------------------------------------
// Fused split-K MFMA attention (validated round-14/16): 512 threads = 8 waves
// = 4 z-chunks x 2 q-halves; T14 prefetch; in-LDS partial merge.
// ---------------------------------------------------------------------------
__global__ __launch_bounds__(512) void k_attn(const ushort* __restrict__ Qs,
                                              const ushort* __restrict__ Ks,
                                              const ushort* __restrict__ Vt,
                                              ushort* __restrict__ O) {
  __shared__ __align__(16) char smem[34816];
  ushort* pm = reinterpret_cast<ushort*>(smem);
  float* pd = reinterpret_cast<float*>(smem + 24576);

  const int tid = threadIdx.x;
  const int l = tid & 63;
  const int wid = tid >> 6;       // 0..7
  const int zc = wid >> 1;        // K chunk 0..3
  const int qh = wid & 1;         // q half 0..1
  const int l31 = l & 31, lhi = l >> 5;
  const int bh = blockIdx.y;
  const int q0 = blockIdx.x * 64 + qh * 32;

  ushort* myp = reinterpret_cast<ushort*>(smem) + wid * (32 * 68);

  FragU aq0, aq1;
  {
    const ushort* qp = Qs + ((size_t)bh * 1024 + q0 + l31) * 32 + lhi * 8;
    aq0.q = *reinterpret_cast<const uint4*>(qp);
    aq1.q = *reinterpret_cast<const uint4*>(qp + 16);
  }

  const ushort* kbase = Ks + (size_t)bh * 1024 * 32;
  const ushort* vbase = Vt + (size_t)bh * 64 * 1024;

  f32x16 oacc0 = 0.0f, oacc1 = 0.0f;
  float pden[16];
#pragma unroll
  for (int r = 0; r < 16; ++r) pden[r] = 0.f;

  const int ktBeg = zc * 4;
  FragU kc00, kc01, kc10, kc11;
  {
    const ushort* kp0 = kbase + (size_t)(ktBeg * 64 + l31) * 32 + lhi * 8;
    const ushort* kp1 = kbase + (size_t)(ktBeg * 64 + 32 + l31) * 32 + lhi * 8;
    kc00.q = *reinterpret_cast<const uint4*>(kp0);
    kc01.q = *reinterpret_cast<const uint4*>(kp0 + 16);
    kc10.q = *reinterpret_cast<const uint4*>(kp1);
    kc11.q = *reinterpret_cast<const uint4*>(kp1 + 16);
  }

#pragma unroll
  for (int ki = 0; ki < 4; ++ki) {
    const int kt = ktBeg + ki;
    const int k0 = kt * 64;

    // ---- issue V loads for this kt (consumed in PV below) ----
    FragU vv00, vv01, vv10, vv11, vv20, vv21, vv30, vv31;
    {
      const ushort* vp = vbase + (size_t)l31 * 1024 + k0 + lhi * 8;
      vv00.q = *reinterpret_cast<const uint4*>(vp);
      vv01.q = *reinterpret_cast<const uint4*>(vp + 32 * 1024);
      vv10.q = *reinterpret_cast<const uint4*>(vp + 16);
      vv11.q = *reinterpret_cast<const uint4*>(vp + 16 + 32 * 1024);
      vv20.q = *reinterpret_cast<const uint4*>(vp + 32);
      vv21.q = *reinterpret_cast<const uint4*>(vp + 32 + 32 * 1024);
      vv30.q = *reinterpret_cast<const uint4*>(vp + 48);
      vv31.q = *reinterpret_cast<const uint4*>(vp + 48 + 32 * 1024);
    }

    // ---- QK^T scores ----
    f32x16 sacc0 = 0.0f, sacc1 = 0.0f;
    sacc0 = MFMA(aq0.v, kc00.v, sacc0);
    sacc0 = MFMA(aq1.v, kc01.v, sacc0);
    sacc1 = MFMA(aq0.v, kc10.v, sacc1);
    sacc1 = MFMA(aq1.v, kc11.v, sacc1);

    // ---- issue K loads for kt+1 ----
    FragU kn00, kn01, kn10, kn11;
    if (ki < 3) {
      const ushort* kp0 = kbase + (size_t)((kt + 1) * 64 + l31) * 32 + lhi * 8;
      const ushort* kp1 =
          kbase + (size_t)((kt + 1) * 64 + 32 + l31) * 32 + lhi * 8;
      kn00.q = *reinterpret_cast<const uint4*>(kp0);
      kn01.q = *reinterpret_cast<const uint4*>(kp0 + 16);
      kn10.q = *reinterpret_cast<const uint4*>(kp1);
      kn11.q = *reinterpret_cast<const uint4*>(kp1 + 16);
    }

    // ---- exp -> den + bf16 P to per-wave LDS ----
#pragma unroll
    for (int r = 0; r < 16; ++r) {
      float e0 = __expf(sacc0[r] * SCALE_F);
      float e1 = __expf(sacc1[r] * SCALE_F);
      pden[r] += e0 + e1;
      int q = (r & 3) + ((r >> 2) << 3) + 4 * lhi;
      myp[q * 68 + l31] = (ushort)rne16(e0);
      myp[q * 68 + 32 + l31] = (ushort)rne16(e1);
    }
    __builtin_amdgcn_wave_barrier();

    // ---- PV ----
#pragma unroll
    for (int kst = 0; kst < 4; ++kst) {
      FragU ap;
      const ushort* pp = myp + l31 * 68 + kst * 16 + lhi * 8;
      uint2 plo = *reinterpret_cast<const uint2*>(pp);
      uint2 phi = *reinterpret_cast<const uint2*>(pp + 4);
      ap.q = make_uint4(plo.x, plo.y, phi.x, phi.y);
      const FragU& b0 = (kst == 0) ? vv00 : (kst == 1) ? vv10 : (kst == 2) ? vv20 : vv30;
      const FragU& b1 = (kst == 0) ? vv01 : (kst == 1) ? vv11 : (kst == 2) ? vv21 : vv31;
      oacc0 = MFMA(ap.v, b0.v, oacc0);
      oacc1 = MFMA(ap.v, b1.v, oacc1);
    }

    if (ki < 3) { kc00 = kn00; kc01 = kn01; kc10 = kn10; kc11 = kn11; }
  }

  // ---- lane-reduce den partials ----
#pragma unroll
  for (int r = 0; r < 16; ++r) {
    float s = pden[r];
    s += __shfl_xor(s, 1);
    s += __shfl_xor(s, 2);
    s += __shfl_xor(s, 4);
    s += __shfl_xor(s, 8);
    s += __shfl_xor(s, 16);
    pden[r] = s;
  }

  // ---- in-LDS merge across z-chunks ----
  __syncthreads();  // all waves done with their P tiles; safe to alias
  if (zc > 0) {
    const int mi = (zc - 1) * 2 + qh;
#pragma unroll
    for (int r = 0; r < 16; ++r) {
      int q = (r & 3) + ((r >> 2) << 3) + 4 * lhi;
      pm[(mi * 32 + q) * 64 + l31] = (ushort)rne16(oacc0[r]);
      pm[(mi * 32 + q) * 64 + 32 + l31] = (ushort)rne16(oacc1[r]);
      if (l31 == 0) pd[mi * 32 + q] = pden[r];
    }
  }
  __syncthreads();
  if (zc == 0) {
    const int b = bh >> 4, h = bh & 15;
#pragma unroll
    for (int r = 0; r < 16; ++r) {
      int q = (r & 3) + ((r >> 2) << 3) + 4 * lhi;
      float v0 = oacc0[r], v1 = oacc1[r], den = pden[r];
#pragma unroll
      for (int zz = 0; zz < 3; ++zz) {
        int mi = zz * 2 + qh;
        v0 += bf2f(pm[(mi * 32 + q) * 64 + l31]);
        v1 += bf2f(pm[(mi * 32 + q) * 64 + 32 + l31]);
        den += pd[mi * 32 + q];
      }
      float rden = 1.0f / den;
      size_t row = ((size_t)(b * 1024 + q0 + q)) * 1024 + h * 64;
      O[row + l31] = (ushort)rne16(v0 * rden);
      O[row + 32 + l31] = (ushort)rne16(v1 * rden);
    }
  }
}

// ---------------------------------------------------------------------------
// Final projection (validated round-10/14/16): depth-2 pipeline.
// ---------------------------------------------------------------------------
__global__ __launch_bounds__(256) void k_final(const ushort* __restrict__ Xb,
                                               const ushort* __restrict__ Wb,
                                               float* __restrict__ Y) {
  __shared__ __align__(16) char smem[16384];

  const int m0 = blockIdx.y * 64;
  const int n0 = blockIdx.x * 64;
  const int tid = threadIdx.x;
  const int l = tid & 63;
  const int wid = tid >> 6;
  const int wr = wid >> 1, wc = wid & 1;
  const int l31 = l & 31, lhi = l >> 5;
  const int sr = tid >> 2;
  const int sc = tid & 3;

  const int offA = sr * 64 + ((sc ^ ((sr >> 1) & 3)) << 4);
  const int offB = 4096 + offA;
  const ushort* apsrc = Xb + (size_t)(m0 + sr) * 1024 + sc * 8;
  const ushort* bpsrc = Wb + (size_t)(n0 + sr) * 1024 + sc * 8;

  f32x16 acc = 0.0f;

  {
    *reinterpret_cast<uint4*>(smem + offA) =
        *reinterpret_cast<const uint4*>(apsrc);
    *reinterpret_cast<uint4*>(smem + offB) =
        *reinterpret_cast<const uint4*>(bpsrc);
  }
  uint4 ra = *reinterpret_cast<const uint4*>(apsrc + 32);
  uint4 rb = *reinterpret_cast<const uint4*>(bpsrc + 32);
  __syncthreads();

  int cur = 0;
#pragma unroll 4
  for (int t = 0; t < 32; ++t) {
    uint4 na, nb;
    if (t < 30) {
      const int kn = (t + 2) * 32;
      na = *reinterpret_cast<const uint4*>(apsrc + kn);
      nb = *reinterpret_cast<const uint4*>(bpsrc + kn);
    }

    const char* base = smem + cur * 8192;
#pragma unroll
    for (int kst = 0; kst < 2; ++kst) {
      FragU ah, bh;
      int row = wr * 32 + l31;
      int cc = (kst * 2 + lhi) ^ ((row >> 1) & 3);
      ah.q = *reinterpret_cast<const uint4*>(base + row * 64 + cc * 16);
      int brow = wc * 32 + l31;
      int bcc = (kst * 2 + lhi) ^ ((brow >> 1) & 3);
      bh.q = *reinterpret_cast<const uint4*>(base + 4096 + brow * 64 + bcc * 16);
      acc = MFMA(ah.v, bh.v, acc);
    }

    if (t < 31) {
      char* dst = smem + (cur ^ 1) * 8192;
      *reinterpret_cast<uint4*>(dst + offA) = ra;
      *reinterpret_cast<uint4*>(dst + offB) = rb;
      __syncthreads();
      cur ^= 1;
      if (t < 30) { ra = na; rb = nb; }
    }
  }

#pragma unroll
  for (int j = 0; j < 16; ++j) {
    int rl = (j & 3) + ((j >> 2) & 3) * 8 + 4 * lhi;
    int m = m0 + wr * 32 + rl;
    Y[(size_t)m * 1024 + n0 + wc * 32 + l31] = acc[j];
  }
}

// ---------------------------------------------------------------------------
extern "C" void kernel_launch(void* const* d_in, const int* in_sizes, int n_in,
                              void* d_out, int out_size, void* d_ws,
                              size_t ws_size, hipStream_t stream) {
  const float* x = (const float*)d_in[0];
  const float* Wq = (const float*)d_in[1];
  const float* Wk = (const float*)d_in[2];
  const float* Wv = (const float*)d_in[3];
  const float* Wo = (const float*)d_in[4];
  const float* tpl = (const float*)d_in[5];
  const float* proj = (const float*)d_in[6];
  float* out = (float*)d_out;

  char* ws = (char*)d_ws;
  size_t off = 0;
  auto alloc = [&](size_t bytes) {
    void* p = ws + off;
    off += (bytes + 255) & ~(size_t)255;
    return p;
  };

  const size_t MB = 1024 * 1024;
  bool big = ws_size >= 22 * MB;

  ushort *Xb, *Wvb, *obuf;
  float* cs;
  ushort *Ahh, *Ahl, *Wqb, *Wkb, *Wob, *qs, *ks, *vt;

  if (big) {
    Xb = (ushort*)alloc(4 * MB);
    cs = (float*)alloc((size_t)1024 * 64 * 4);
    Ahh = (ushort*)alloc((size_t)16 * 32 * 64 * 2);
    Ahl = (ushort*)alloc((size_t)16 * 32 * 64 * 2);
    Wqb = (ushort*)alloc(2 * MB);
    Wkb = (ushort*)alloc(2 * MB);
    Wvb = (ushort*)alloc(2 * MB);
    Wob = (ushort*)alloc(2 * MB);
    qs = (ushort*)alloc(2 * MB);
    ks = (ushort*)alloc(2 * MB);
    vt = (ushort*)alloc(4 * MB);
    obuf = Xb;  // Xb dead after k_qkv
  } else {
    cs = (float*)alloc((size_t)1024 * 64 * 4);
    Ahh = (ushort*)alloc((size_t)16 * 32 * 64 * 2);
    Ahl = (ushort*)alloc((size_t)16 * 32 * 64 * 2);
    Wqb = (ushort*)alloc(2 * MB);
    Wkb = (ushort*)alloc(2 * MB);
    Wob = (ushort*)alloc(2 * MB);
    qs = (ushort*)alloc(2 * MB);
    ks = (ushort*)alloc(2 * MB);
    vt = (ushort*)alloc(4 * MB);
    obuf = (ushort*)ws;  // aliases [cs..Wkb] (dead after k_qkv)
    Xb = (ushort*)d_out;
    Wvb = (ushort*)((char*)d_out + 4 * MB);
  }

  k_prep<<<dim3(3328), dim3(256), 0, stream>>>(x, Wq, Wk, Wv, Wo, tpl, proj,
                                               Xb, Wqb, Wkb, Wvb, Wob, cs, Ahh,
                                               Ahl);
  k_qkv<<<dim3(16, 16, 3), dim3(256), 0, stream>>>(Xb, Wqb, Wkb, Wvb, Ahh, Ahl,
                                                   cs, qs, ks, vt);
  k_attn<<<dim3(16, 32), dim3(512), 0, stream>>>(qs, ks, vt, obuf);
  k_final<<<dim3(16, 32), dim3(256), 0, stream>>>(obuf, Wob, out);
}